// Round 7
// baseline (222.958 us; speedup 1.0000x reference)
//
#include <hip/hip_runtime.h>
#include <math.h>

#define BB 1024
#define NN 512
#define MM 256
#define OUTROW (NN + MM + NN * MM)   // 131840
#define EPS_ADD 1e-16f
#define EPS_COS 1e-8f
#define G_REG 11                     // register-resident groups per wave (44 rows)
#define G_TOT 16                     // total 4-row groups per wave (64 rows)

typedef float f4v __attribute__((ext_vector_type(4)));

__device__ inline float waveReduceSum(float v) {
#pragma unroll
    for (int off = 32; off > 0; off >>= 1) v += __shfl_xor(v, off);
    return v;
}
__device__ inline float waveReduceMax(float v) {
#pragma unroll
    for (int off = 32; off > 0; off >>= 1) v = fmaxf(v, __shfl_xor(v, off));
    return v;
}

__device__ __forceinline__ void ldgrp(f4v (&buf)[4], const float* __restrict__ rp) {
#pragma unroll
    for (int mc = 0; mc < 4; ++mc)
        buf[mc] = *reinterpret_cast<const f4v*>(rp + mc * 64);
}
__device__ __forceinline__ void ldgrp_nt(f4v (&buf)[4], const float* __restrict__ rp) {
#pragma unroll
    for (int mc = 0; mc < 4; ++mc)
        buf[mc] = __builtin_nontemporal_load(reinterpret_cast<const f4v*>(rp + mc * 64));
}

__device__ __forceinline__ void redgrp(const f4v (&buf)[4], const f4v (&kf)[4],
                                       float bet, float kn, float* __restrict__ sc,
                                       int row, int sl) {
    float dot = 0.f, ssq = 0.f;
#pragma unroll
    for (int mc = 0; mc < 4; ++mc) {
        const float mx = buf[mc].x + EPS_ADD, my = buf[mc].y + EPS_ADD;
        const float mz = buf[mc].z + EPS_ADD, mw = buf[mc].w + EPS_ADD;
        dot += mx * kf[mc].x + my * kf[mc].y + mz * kf[mc].z + mw * kf[mc].w;
        ssq += mx * mx + my * my + mz * mz + mw * mw;
    }
#pragma unroll
    for (int off = 8; off > 0; off >>= 1) {
        dot += __shfl_xor(dot, off);
        ssq += __shfl_xor(ssq, off);
    }
    if (sl == 0)
        sc[row] = bet * dot / (fmaxf(sqrtf(ssq), EPS_COS) * kn);
}

__device__ __forceinline__ void procgrp(const f4v (&mvv)[4], float wn,
                                        const f4v (&ev)[4], const f4v (&av)[4],
                                        f4v (&acc)[4], float* __restrict__ op) {
#pragma unroll
    for (int mc = 0; mc < 4; ++mc) {
        const f4v nm = mvv[mc] * (1.f - wn * ev[mc]) + wn * av[mc];
        __builtin_nontemporal_store(nm, reinterpret_cast<f4v*>(op + mc * 64));
        acc[mc] += wn * mvv[mc];
    }
}

// softmax + gate + circular conv + sharpen; fills wf and writes w output.
// Contains barriers — must be reached by all 512 threads.
__device__ __forceinline__ void weight_pipeline(
    int t, int lane, int wave,
    float gv, float gam, float s0, float s1, float s2,
    const float* __restrict__ wprow, float* __restrict__ outb,
    float* __restrict__ sc, float* __restrict__ wg, float* __restrict__ wf,
    float* __restrict__ red) {
    const float v = sc[t];
    {
        const float m1 = waveReduceMax(v);
        if (lane == 0) red[wave] = m1;
    }
    __syncthreads();
    float mmax = red[0];
#pragma unroll
    for (int k = 1; k < 8; k++) mmax = fmaxf(mmax, red[k]);
    const float ex = expf(v - mmax);
    __syncthreads();
    {
        const float s1w = waveReduceSum(ex);
        if (lane == 0) red[wave] = s1w;
    }
    __syncthreads();
    float esum = 0.f;
#pragma unroll
    for (int k = 0; k < 8; k++) esum += red[k];
    const float w_c = ex / esum;
    wg[t] = gv * w_c + (1.f - gv) * wprow[t];
    __syncthreads();
    const float wt = wg[(t + NN - 1) & (NN - 1)] * s0 + wg[t] * s1 +
                     wg[(t + 1) & (NN - 1)] * s2;
    const float wp = powf(wt, gam);
    __syncthreads();
    {
        const float sw = waveReduceSum(wp);
        if (lane == 0) red[wave] = sw;
    }
    __syncthreads();
    float wsum = 0.f;
#pragma unroll
    for (int k = 0; k < 8; k++) wsum += red[k];
    const float wv = wp / (wsum + EPS_ADD);
    wf[t]   = wv;
    outb[t] = wv;
    __syncthreads();
}

__global__ __launch_bounds__(512, 2) void ntm_memory_kernel(
    const float* __restrict__ memory, const float* __restrict__ key,
    const float* __restrict__ beta, const float* __restrict__ g,
    const float* __restrict__ s, const float* __restrict__ gamma,
    const float* __restrict__ w_prev, const float* __restrict__ e,
    const float* __restrict__ a, float* __restrict__ out) {
    const int b0   = blockIdx.x;           // batches b0 and b0+512
    const int b1   = blockIdx.x + (BB / 2);
    const int t    = threadIdx.x;
    const int lane = t & 63;
    const int wave = t >> 6;
    const int sub  = lane >> 4;
    const int sl   = lane & 15;

    __shared__ float key_lds[MM];
    __shared__ float sc[NN];
    __shared__ float wg[NN];
    __shared__ float wf[NN];
    __shared__ float ea_lds[2 * MM];
    __shared__ float red[8];
    __shared__ float rpart[8][MM];

    const int rowbase = wave * 64 + sub;
    const float* __restrict__ memb0 = memory + (size_t)b0 * NN * MM;
    const float* __restrict__ memb1 = memory + (size_t)b1 * NN * MM;
    const float* __restrict__ rp0 = memb0 + (size_t)rowbase * MM + sl * 4;
    const float* __restrict__ rp1 = memb1 + (size_t)rowbase * MM + sl * 4;
    float* __restrict__ outb0 = out + (size_t)b0 * OUTROW;
    float* __restrict__ outb1 = out + (size_t)b1 * OUTROW;

    f4v tile[G_REG][4];

    // ================= BATCH 0 =================
    // ---- stage key0(+eps), e0, a0 ----
    if (t < MM) {
        key_lds[t]     = key[b0 * MM + t] + EPS_ADD;
        ea_lds[MM + t] = a[b0 * MM + t];
    } else {
        ea_lds[t - MM] = e[b0 * MM + (t - MM)];
    }
    __syncthreads();
    if (t < MM) {
        const float kv = key_lds[t];
        const float ss = waveReduceSum(kv * kv);
        if (lane == 0) red[wave] = ss;
    }
    __syncthreads();
    const float kn0 = fmaxf(sqrtf(red[0] + red[1] + red[2] + red[3]), EPS_COS);
    const float bet0 = beta[b0], gv0 = g[b0], gam0 = gamma[b0];
    const float s00 = s[b0 * 3 + 0], s01 = s[b0 * 3 + 1], s02 = s[b0 * 3 + 2];
    __syncthreads();   // red reuse

    {
        f4v kf[4];
#pragma unroll
        for (int mc = 0; mc < 4; ++mc)
            kf[mc] = *reinterpret_cast<const f4v*>(&key_lds[mc * 64 + sl * 4]);

        // phase 1a: register tile (44 live-out NT loads)
#pragma unroll
        for (int gp = 0; gp < G_REG; ++gp)
            ldgrp_nt(tile[gp], rp0 + (size_t)(4 * gp) * MM);
#pragma unroll
        for (int gp = 0; gp < G_REG; ++gp)
            redgrp(tile[gp], kf, bet0, kn0, sc, rowbase + 4 * gp, sl);

        // phase 1b: 5 streaming groups (cacheable), 2-deep
        f4v sA[4], sB[4];
        ldgrp(sA, rp0 + (size_t)(4 * (G_REG + 0)) * MM);
        ldgrp(sB, rp0 + (size_t)(4 * (G_REG + 1)) * MM);
        redgrp(sA, kf, bet0, kn0, sc, rowbase + 4 * (G_REG + 0), sl);
        ldgrp(sA, rp0 + (size_t)(4 * (G_REG + 2)) * MM);
        redgrp(sB, kf, bet0, kn0, sc, rowbase + 4 * (G_REG + 1), sl);
        ldgrp(sB, rp0 + (size_t)(4 * (G_REG + 3)) * MM);
        redgrp(sA, kf, bet0, kn0, sc, rowbase + 4 * (G_REG + 2), sl);
        ldgrp(sA, rp0 + (size_t)(4 * (G_REG + 4)) * MM);
        redgrp(sB, kf, bet0, kn0, sc, rowbase + 4 * (G_REG + 3), sl);
        redgrp(sA, kf, bet0, kn0, sc, rowbase + 4 * (G_REG + 4), sl);
    }
    __syncthreads();

    weight_pipeline(t, lane, wave, gv0, gam0, s00, s01, s02,
                    w_prev + (size_t)b0 * NN, outb0, sc, wg, wf, red);

    // ---- phase 2 (b0): stores; then launch b1's tile loads into the drain ----
    {
        f4v ev[4], av[4], acc[4];
#pragma unroll
        for (int mc = 0; mc < 4; ++mc) {
            ev[mc]  = *reinterpret_cast<const f4v*>(&ea_lds[mc * 64 + sl * 4]);
            av[mc]  = *reinterpret_cast<const f4v*>(&ea_lds[MM + mc * 64 + sl * 4]);
            acc[mc] = (f4v)0.f;
        }
        float* __restrict__ ob0 = outb0 + (NN + MM) + (size_t)rowbase * MM + sl * 4;
#pragma unroll
        for (int gp = 0; gp < G_REG; ++gp)
            procgrp(tile[gp], wf[rowbase + 4 * gp], ev, av, acc,
                    ob0 + (size_t)(4 * gp) * MM);
        {   // streaming groups: L2 re-read + store (complete BEFORE b1 burst)
            f4v sA[4], sB[4];
            ldgrp(sA, rp0 + (size_t)(4 * (G_REG + 0)) * MM);
            ldgrp(sB, rp0 + (size_t)(4 * (G_REG + 1)) * MM);
            procgrp(sA, wf[rowbase + 4 * (G_REG + 0)], ev, av, acc,
                    ob0 + (size_t)(4 * (G_REG + 0)) * MM);
            ldgrp(sA, rp0 + (size_t)(4 * (G_REG + 2)) * MM);
            procgrp(sB, wf[rowbase + 4 * (G_REG + 1)], ev, av, acc,
                    ob0 + (size_t)(4 * (G_REG + 1)) * MM);
            ldgrp(sB, rp0 + (size_t)(4 * (G_REG + 3)) * MM);
            procgrp(sA, wf[rowbase + 4 * (G_REG + 2)], ev, av, acc,
                    ob0 + (size_t)(4 * (G_REG + 2)) * MM);
            ldgrp(sA, rp0 + (size_t)(4 * (G_REG + 4)) * MM);
            procgrp(sB, wf[rowbase + 4 * (G_REG + 3)], ev, av, acc,
                    ob0 + (size_t)(4 * (G_REG + 3)) * MM);
            procgrp(sA, wf[rowbase + 4 * (G_REG + 4)], ev, av, acc,
                    ob0 + (size_t)(4 * (G_REG + 4)) * MM);
        }

        // ---- issue b1 register-tile loads NOW (overlaps b0 store drain) ----
#pragma unroll
        for (int gp = 0; gp < G_REG; ++gp)
            ldgrp_nt(tile[gp], rp1 + (size_t)(4 * gp) * MM);

        // ---- r0 reduce while loads fly ----
#pragma unroll
        for (int mc = 0; mc < 4; ++mc) {
            acc[mc].x += __shfl_xor(acc[mc].x, 16); acc[mc].y += __shfl_xor(acc[mc].y, 16);
            acc[mc].z += __shfl_xor(acc[mc].z, 16); acc[mc].w += __shfl_xor(acc[mc].w, 16);
            acc[mc].x += __shfl_xor(acc[mc].x, 32); acc[mc].y += __shfl_xor(acc[mc].y, 32);
            acc[mc].z += __shfl_xor(acc[mc].z, 32); acc[mc].w += __shfl_xor(acc[mc].w, 32);
        }
        if (sub == 0) {
#pragma unroll
            for (int mc = 0; mc < 4; ++mc)
                *reinterpret_cast<f4v*>(&rpart[wave][mc * 64 + sl * 4]) = acc[mc];
        }
    }
    __syncthreads();
    if (t < MM) {
        float rsum = 0.f;
#pragma unroll
        for (int k = 0; k < 8; k++) rsum += rpart[k][t];
        outb0[NN + t] = rsum;
    }

    // ================= BATCH 1 =================
    // ---- restage key1(+eps), e1, a1 (covers b1 tile-load latency) ----
    if (t < MM) {
        key_lds[t]     = key[b1 * MM + t] + EPS_ADD;
        ea_lds[MM + t] = a[b1 * MM + t];
    } else {
        ea_lds[t - MM] = e[b1 * MM + (t - MM)];
    }
    __syncthreads();
    if (t < MM) {
        const float kv = key_lds[t];
        const float ss = waveReduceSum(kv * kv);
        if (lane == 0) red[wave] = ss;
    }
    __syncthreads();
    const float kn1 = fmaxf(sqrtf(red[0] + red[1] + red[2] + red[3]), EPS_COS);
    const float bet1 = beta[b1], gv1 = g[b1], gam1 = gamma[b1];
    const float s10 = s[b1 * 3 + 0], s11 = s[b1 * 3 + 1], s12 = s[b1 * 3 + 2];
    __syncthreads();   // red reuse

    {
        f4v kf[4];
#pragma unroll
        for (int mc = 0; mc < 4; ++mc)
            kf[mc] = *reinterpret_cast<const f4v*>(&key_lds[mc * 64 + sl * 4]);

        // tile already loaded — just reduce
#pragma unroll
        for (int gp = 0; gp < G_REG; ++gp)
            redgrp(tile[gp], kf, bet1, kn1, sc, rowbase + 4 * gp, sl);

        f4v sA[4], sB[4];
        ldgrp(sA, rp1 + (size_t)(4 * (G_REG + 0)) * MM);
        ldgrp(sB, rp1 + (size_t)(4 * (G_REG + 1)) * MM);
        redgrp(sA, kf, bet1, kn1, sc, rowbase + 4 * (G_REG + 0), sl);
        ldgrp(sA, rp1 + (size_t)(4 * (G_REG + 2)) * MM);
        redgrp(sB, kf, bet1, kn1, sc, rowbase + 4 * (G_REG + 1), sl);
        ldgrp(sB, rp1 + (size_t)(4 * (G_REG + 3)) * MM);
        redgrp(sA, kf, bet1, kn1, sc, rowbase + 4 * (G_REG + 2), sl);
        ldgrp(sA, rp1 + (size_t)(4 * (G_REG + 4)) * MM);
        redgrp(sB, kf, bet1, kn1, sc, rowbase + 4 * (G_REG + 3), sl);
        redgrp(sA, kf, bet1, kn1, sc, rowbase + 4 * (G_REG + 4), sl);
    }
    __syncthreads();

    weight_pipeline(t, lane, wave, gv1, gam1, s10, s11, s12,
                    w_prev + (size_t)b1 * NN, outb1, sc, wg, wf, red);

    // ---- phase 2 (b1) ----
    {
        f4v ev[4], av[4], acc[4];
#pragma unroll
        for (int mc = 0; mc < 4; ++mc) {
            ev[mc]  = *reinterpret_cast<const f4v*>(&ea_lds[mc * 64 + sl * 4]);
            av[mc]  = *reinterpret_cast<const f4v*>(&ea_lds[MM + mc * 64 + sl * 4]);
            acc[mc] = (f4v)0.f;
        }
        float* __restrict__ ob1 = outb1 + (NN + MM) + (size_t)rowbase * MM + sl * 4;
#pragma unroll
        for (int gp = 0; gp < G_REG; ++gp)
            procgrp(tile[gp], wf[rowbase + 4 * gp], ev, av, acc,
                    ob1 + (size_t)(4 * gp) * MM);
        {
            f4v sA[4], sB[4];
            ldgrp(sA, rp1 + (size_t)(4 * (G_REG + 0)) * MM);
            ldgrp(sB, rp1 + (size_t)(4 * (G_REG + 1)) * MM);
            procgrp(sA, wf[rowbase + 4 * (G_REG + 0)], ev, av, acc,
                    ob1 + (size_t)(4 * (G_REG + 0)) * MM);
            ldgrp(sA, rp1 + (size_t)(4 * (G_REG + 2)) * MM);
            procgrp(sB, wf[rowbase + 4 * (G_REG + 1)], ev, av, acc,
                    ob1 + (size_t)(4 * (G_REG + 1)) * MM);
            ldgrp(sB, rp1 + (size_t)(4 * (G_REG + 3)) * MM);
            procgrp(sA, wf[rowbase + 4 * (G_REG + 2)], ev, av, acc,
                    ob1 + (size_t)(4 * (G_REG + 2)) * MM);
            ldgrp(sA, rp1 + (size_t)(4 * (G_REG + 4)) * MM);
            procgrp(sB, wf[rowbase + 4 * (G_REG + 3)], ev, av, acc,
                    ob1 + (size_t)(4 * (G_REG + 3)) * MM);
            procgrp(sA, wf[rowbase + 4 * (G_REG + 4)], ev, av, acc,
                    ob1 + (size_t)(4 * (G_REG + 4)) * MM);
        }
#pragma unroll
        for (int mc = 0; mc < 4; ++mc) {
            acc[mc].x += __shfl_xor(acc[mc].x, 16); acc[mc].y += __shfl_xor(acc[mc].y, 16);
            acc[mc].z += __shfl_xor(acc[mc].z, 16); acc[mc].w += __shfl_xor(acc[mc].w, 16);
            acc[mc].x += __shfl_xor(acc[mc].x, 32); acc[mc].y += __shfl_xor(acc[mc].y, 32);
            acc[mc].z += __shfl_xor(acc[mc].z, 32); acc[mc].w += __shfl_xor(acc[mc].w, 32);
        }
        if (sub == 0) {
#pragma unroll
            for (int mc = 0; mc < 4; ++mc)
                *reinterpret_cast<f4v*>(&rpart[wave][mc * 64 + sl * 4]) = acc[mc];
        }
    }
    __syncthreads();
    if (t < MM) {
        float rsum = 0.f;
#pragma unroll
        for (int k = 0; k < 8; k++) rsum += rpart[k][t];
        outb1[NN + t] = rsum;
    }
}

extern "C" void kernel_launch(void* const* d_in, const int* in_sizes, int n_in,
                              void* d_out, int out_size, void* d_ws, size_t ws_size,
                              hipStream_t stream) {
    const float* memory = (const float*)d_in[0];
    const float* key    = (const float*)d_in[1];
    const float* beta   = (const float*)d_in[2];
    const float* g      = (const float*)d_in[3];
    const float* s      = (const float*)d_in[4];
    const float* gamma  = (const float*)d_in[5];
    const float* w_prev = (const float*)d_in[6];
    const float* e      = (const float*)d_in[7];
    const float* a      = (const float*)d_in[8];
    float* out = (float*)d_out;

    ntm_memory_kernel<<<BB / 2, 512, 0, stream>>>(memory, key, beta, g, s, gamma,
                                                  w_prev, e, a, out);
}

// Round 8
// 213.953 us; speedup vs baseline: 1.0421x; 1.0421x over previous
//
#include <hip/hip_runtime.h>
#include <math.h>

#define BB 1024
#define NN 512
#define MM 256
#define OUTROW (NN + MM + NN * MM)   // 131840
#define EPS_ADD 1e-16f
#define EPS_COS 1e-8f
#define G_REG 11                     // register-resident groups per wave (44 rows)
#define G_LDS 4                      // LDS-resident groups per wave (16 rows)
#define G_TOT 16                     // total 4-row groups per wave (64 rows)

typedef float f4v __attribute__((ext_vector_type(4)));

__device__ inline float waveReduceSum(float v) {
#pragma unroll
    for (int off = 32; off > 0; off >>= 1) v += __shfl_xor(v, off);
    return v;
}
__device__ inline float waveReduceMax(float v) {
#pragma unroll
    for (int off = 32; off > 0; off >>= 1) v = fmaxf(v, __shfl_xor(v, off));
    return v;
}

__device__ __forceinline__ void ldgrp(f4v (&buf)[4], const float* __restrict__ rp) {
#pragma unroll
    for (int mc = 0; mc < 4; ++mc)
        buf[mc] = *reinterpret_cast<const f4v*>(rp + mc * 64);
}
__device__ __forceinline__ void ldgrp_nt(f4v (&buf)[4], const float* __restrict__ rp) {
#pragma unroll
    for (int mc = 0; mc < 4; ++mc)
        buf[mc] = __builtin_nontemporal_load(reinterpret_cast<const f4v*>(rp + mc * 64));
}
// LDS slab helpers: each (wave,gl,sub) owns 64 f4v; lane sl touches mc*16+sl
__device__ __forceinline__ void stgrp_lds(f4v* __restrict__ dst,
                                          const f4v (&buf)[4], int sl) {
#pragma unroll
    for (int mc = 0; mc < 4; ++mc) dst[mc * 16 + sl] = buf[mc];
}
__device__ __forceinline__ void ldgrp_lds(f4v (&buf)[4],
                                          const f4v* __restrict__ src, int sl) {
#pragma unroll
    for (int mc = 0; mc < 4; ++mc) buf[mc] = src[mc * 16 + sl];
}

__device__ __forceinline__ void redgrp(const f4v (&buf)[4], const f4v (&kf)[4],
                                       float bet, float kn, float* __restrict__ sc,
                                       int row, int sl) {
    float dot = 0.f, ssq = 0.f;
#pragma unroll
    for (int mc = 0; mc < 4; ++mc) {
        const float mx = buf[mc].x + EPS_ADD, my = buf[mc].y + EPS_ADD;
        const float mz = buf[mc].z + EPS_ADD, mw = buf[mc].w + EPS_ADD;
        dot += mx * kf[mc].x + my * kf[mc].y + mz * kf[mc].z + mw * kf[mc].w;
        ssq += mx * mx + my * my + mz * mz + mw * mw;
    }
#pragma unroll
    for (int off = 8; off > 0; off >>= 1) {
        dot += __shfl_xor(dot, off);
        ssq += __shfl_xor(ssq, off);
    }
    if (sl == 0)
        sc[row] = bet * dot / (fmaxf(sqrtf(ssq), EPS_COS) * kn);
}

__device__ __forceinline__ void procgrp(const f4v (&mvv)[4], float wn,
                                        const f4v (&ev)[4], const f4v (&av)[4],
                                        f4v (&acc)[4], float* __restrict__ op) {
#pragma unroll
    for (int mc = 0; mc < 4; ++mc) {
        const f4v nm = mvv[mc] * (1.f - wn * ev[mc]) + wn * av[mc];
        __builtin_nontemporal_store(nm, reinterpret_cast<f4v*>(op + mc * 64));
        acc[mc] += wn * mvv[mc];
    }
}

__global__ __launch_bounds__(512, 2) void ntm_memory_kernel(
    const float* __restrict__ memory, const float* __restrict__ key,
    const float* __restrict__ beta, const float* __restrict__ g,
    const float* __restrict__ s, const float* __restrict__ gamma,
    const float* __restrict__ w_prev, const float* __restrict__ e,
    const float* __restrict__ a, float* __restrict__ out) {
    const int b    = blockIdx.x;
    const int t    = threadIdx.x;
    const int lane = t & 63;
    const int wave = t >> 6;          // 0..7
    const int sub  = lane >> 4;       // 0..3  row within group
    const int sl   = lane & 15;       // 0..15 lanes per row

    __shared__ float key_lds[MM];
    __shared__ float sc[NN];
    __shared__ float wg[NN];
    __shared__ float wf[NN];
    __shared__ float ea_lds[2 * MM];
    __shared__ float red[8];
    __shared__ float rpart[8][MM];
    __shared__ f4v   TL[8][G_LDS][4][MM / 4];   // 128 KB wave-private row tile

    const float* __restrict__ memb = memory + (size_t)b * NN * MM;
    float* __restrict__ outb       = out + (size_t)b * OUTROW;

    // ---- stage key (+eps), e, a ----
    if (t < MM) {
        key_lds[t]      = key[b * MM + t] + EPS_ADD;
        ea_lds[MM + t]  = a[b * MM + t];
    } else {
        const int i = t - MM;
        ea_lds[i] = e[b * MM + i];
    }
    __syncthreads();

    // ---- key norm ----
    if (t < MM) {
        float kv = key_lds[t];
        float ss = waveReduceSum(kv * kv);
        if (lane == 0) red[wave] = ss;
    }
    __syncthreads();
    const float kn  = fmaxf(sqrtf(red[0] + red[1] + red[2] + red[3]), EPS_COS);
    const float bet = beta[b];
    const float gv  = g[b];
    const float gam = gamma[b];
    const float s0  = s[b * 3 + 0];
    const float s1  = s[b * 3 + 1];
    const float s2  = s[b * 3 + 2];
    __syncthreads();   // red about to be reused

    const int rowbase = wave * 64 + sub;          // row of group gp = rowbase + 4*gp
    const float* __restrict__ rp0 = memb + (size_t)rowbase * MM + sl * 4;

    f4v kf[4];
#pragma unroll
    for (int mc = 0; mc < 4; ++mc)
        kf[mc] = *reinterpret_cast<const f4v*>(&key_lds[mc * 64 + sl * 4]);

    // ---- phase 1a: register tile (44 live-out NT loads => deep MLP) ----
    f4v tile[G_REG][4];
#pragma unroll
    for (int gp = 0; gp < G_REG; ++gp)
        ldgrp_nt(tile[gp], rp0 + (size_t)(4 * gp) * MM);

    // issue first two LDS-group loads behind the tile burst
    f4v bufA[4], bufB[4];
    ldgrp_nt(bufA, rp0 + (size_t)(4 * (G_REG + 0)) * MM);
    ldgrp_nt(bufB, rp0 + (size_t)(4 * (G_REG + 1)) * MM);

    // reduce register groups (vmcnt staggers through the burst)
#pragma unroll
    for (int gp = 0; gp < G_REG; ++gp)
        redgrp(tile[gp], kf, bet, kn, sc, rowbase + 4 * gp, sl);

    // ---- phase 1b: 4 LDS groups (stage + reduce) + 1 streaming group ----
    stgrp_lds(&TL[wave][0][sub][0], bufA, sl);
    redgrp(bufA, kf, bet, kn, sc, rowbase + 4 * (G_REG + 0), sl);
    ldgrp_nt(bufA, rp0 + (size_t)(4 * (G_REG + 2)) * MM);

    stgrp_lds(&TL[wave][1][sub][0], bufB, sl);
    redgrp(bufB, kf, bet, kn, sc, rowbase + 4 * (G_REG + 1), sl);
    ldgrp_nt(bufB, rp0 + (size_t)(4 * (G_REG + 3)) * MM);

    stgrp_lds(&TL[wave][2][sub][0], bufA, sl);
    redgrp(bufA, kf, bet, kn, sc, rowbase + 4 * (G_REG + 2), sl);
    ldgrp(bufA, rp0 + (size_t)(4 * (G_REG + 4)) * MM);   // streaming grp 15, cacheable

    stgrp_lds(&TL[wave][3][sub][0], bufB, sl);
    redgrp(bufB, kf, bet, kn, sc, rowbase + 4 * (G_REG + 3), sl);

    redgrp(bufA, kf, bet, kn, sc, rowbase + 4 * (G_REG + 4), sl);
    __syncthreads();

    // ---- softmax over N=512 (thread t owns element t) ----
    const float v = sc[t];
    {
        float m1 = waveReduceMax(v);
        if (lane == 0) red[wave] = m1;
    }
    __syncthreads();
    float mmax = red[0];
#pragma unroll
    for (int k = 1; k < 8; k++) mmax = fmaxf(mmax, red[k]);
    const float ex = expf(v - mmax);
    __syncthreads();
    {
        float s1w = waveReduceSum(ex);
        if (lane == 0) red[wave] = s1w;
    }
    __syncthreads();
    float esum = 0.f;
#pragma unroll
    for (int k = 0; k < 8; k++) esum += red[k];
    const float w_c = ex / esum;

    // ---- gate + circular conv + sharpen ----
    wg[t] = gv * w_c + (1.f - gv) * w_prev[b * NN + t];
    __syncthreads();
    const float wt = wg[(t + NN - 1) & (NN - 1)] * s0 + wg[t] * s1 +
                     wg[(t + 1) & (NN - 1)] * s2;
    const float wp = powf(wt, gam);
    __syncthreads();
    {
        float sw = waveReduceSum(wp);
        if (lane == 0) red[wave] = sw;
    }
    __syncthreads();
    float wsum = 0.f;
#pragma unroll
    for (int k = 0; k < 8; k++) wsum += red[k];
    const float wv = wp / (wsum + EPS_ADD);
    wf[t]   = wv;
    outb[t] = wv;      // output w
    __syncthreads();

    // ---- phase 2: new_mem + r ----
    f4v ev[4], av[4], acc[4];
#pragma unroll
    for (int mc = 0; mc < 4; ++mc) {
        ev[mc]  = *reinterpret_cast<const f4v*>(&ea_lds[mc * 64 + sl * 4]);
        av[mc]  = *reinterpret_cast<const f4v*>(&ea_lds[MM + mc * 64 + sl * 4]);
        acc[mc] = (f4v)0.f;
    }
    float* __restrict__ ob0 = outb + (NN + MM) + (size_t)rowbase * MM + sl * 4;

    // issue the single streaming re-read early (L3 latency hides under stores)
    f4v sS[4];
    ldgrp(sS, rp0 + (size_t)(4 * (G_REG + 4)) * MM);

    // register-resident groups: pure compute + NT store
#pragma unroll
    for (int gp = 0; gp < G_REG; ++gp)
        procgrp(tile[gp], wf[rowbase + 4 * gp], ev, av, acc,
                ob0 + (size_t)(4 * gp) * MM);

    // LDS-resident groups
#pragma unroll
    for (int gl = 0; gl < G_LDS; ++gl) {
        f4v bufL[4];
        ldgrp_lds(bufL, &TL[wave][gl][sub][0], sl);
        procgrp(bufL, wf[rowbase + 4 * (G_REG + gl)], ev, av, acc,
                ob0 + (size_t)(4 * (G_REG + gl)) * MM);
    }
    // streaming group
    procgrp(sS, wf[rowbase + 4 * (G_REG + 4)], ev, av, acc,
            ob0 + (size_t)(4 * (G_REG + 4)) * MM);

    // reduce r partials across the 4 sub-rows of the wave
#pragma unroll
    for (int mc = 0; mc < 4; ++mc) {
        acc[mc].x += __shfl_xor(acc[mc].x, 16); acc[mc].y += __shfl_xor(acc[mc].y, 16);
        acc[mc].z += __shfl_xor(acc[mc].z, 16); acc[mc].w += __shfl_xor(acc[mc].w, 16);
        acc[mc].x += __shfl_xor(acc[mc].x, 32); acc[mc].y += __shfl_xor(acc[mc].y, 32);
        acc[mc].z += __shfl_xor(acc[mc].z, 32); acc[mc].w += __shfl_xor(acc[mc].w, 32);
    }
    if (sub == 0) {
#pragma unroll
        for (int mc = 0; mc < 4; ++mc)
            *reinterpret_cast<f4v*>(&rpart[wave][mc * 64 + sl * 4]) = acc[mc];
    }
    __syncthreads();
    if (t < MM) {
        float rsum = 0.f;
#pragma unroll
        for (int k = 0; k < 8; k++) rsum += rpart[k][t];
        outb[NN + t] = rsum;   // output r
    }
}

extern "C" void kernel_launch(void* const* d_in, const int* in_sizes, int n_in,
                              void* d_out, int out_size, void* d_ws, size_t ws_size,
                              hipStream_t stream) {
    const float* memory = (const float*)d_in[0];
    const float* key    = (const float*)d_in[1];
    const float* beta   = (const float*)d_in[2];
    const float* g      = (const float*)d_in[3];
    const float* s      = (const float*)d_in[4];
    const float* gamma  = (const float*)d_in[5];
    const float* w_prev = (const float*)d_in[6];
    const float* e      = (const float*)d_in[7];
    const float* a      = (const float*)d_in[8];
    float* out = (float*)d_out;

    ntm_memory_kernel<<<BB, 512, 0, stream>>>(memory, key, beta, g, s, gamma,
                                              w_prev, e, a, out);
}

// Round 9
// 207.969 us; speedup vs baseline: 1.0721x; 1.0288x over previous
//
#include <hip/hip_runtime.h>
#include <math.h>

#define BB 1024
#define NN 512
#define MM 256
#define OUTROW (NN + MM + NN * MM)   // 131840
#define EPS_ADD 1e-16f
#define EPS_COS 1e-8f
#define G_REG 11                     // register-resident groups per wave (44 rows)
#define G_TOT 16                     // total 4-row groups per wave (64 rows)

typedef float f4v __attribute__((ext_vector_type(4)));

__device__ inline float waveReduceSum(float v) {
#pragma unroll
    for (int off = 32; off > 0; off >>= 1) v += __shfl_xor(v, off);
    return v;
}

__device__ __forceinline__ void ldgrp(f4v (&buf)[4], const float* __restrict__ rp) {
#pragma unroll
    for (int mc = 0; mc < 4; ++mc)
        buf[mc] = *reinterpret_cast<const f4v*>(rp + mc * 64);
}
__device__ __forceinline__ void ldgrp_nt(f4v (&buf)[4], const float* __restrict__ rp) {
#pragma unroll
    for (int mc = 0; mc < 4; ++mc)
        buf[mc] = __builtin_nontemporal_load(reinterpret_cast<const f4v*>(rp + mc * 64));
}

__device__ __forceinline__ void redgrp(const f4v (&buf)[4], const f4v (&kf)[4],
                                       float bet, float kn, float* __restrict__ sc,
                                       int row, int sl) {
    float dot = 0.f, ssq = 0.f;
#pragma unroll
    for (int mc = 0; mc < 4; ++mc) {
        const float mx = buf[mc].x + EPS_ADD, my = buf[mc].y + EPS_ADD;
        const float mz = buf[mc].z + EPS_ADD, mw = buf[mc].w + EPS_ADD;
        dot += mx * kf[mc].x + my * kf[mc].y + mz * kf[mc].z + mw * kf[mc].w;
        ssq += mx * mx + my * my + mz * mz + mw * mw;
    }
#pragma unroll
    for (int off = 8; off > 0; off >>= 1) {
        dot += __shfl_xor(dot, off);
        ssq += __shfl_xor(ssq, off);
    }
    if (sl == 0)
        sc[row] = bet * dot / (fmaxf(sqrtf(ssq), EPS_COS) * kn);
}

__device__ __forceinline__ void procgrp(const f4v (&mvv)[4], float wn,
                                        const f4v (&ev)[4], const f4v (&av)[4],
                                        f4v (&acc)[4], float* __restrict__ op) {
#pragma unroll
    for (int mc = 0; mc < 4; ++mc) {
        const f4v nm = mvv[mc] * (1.f - wn * ev[mc]) + wn * av[mc];
        __builtin_nontemporal_store(nm, reinterpret_cast<f4v*>(op + mc * 64));
        acc[mc] += wn * mvv[mc];
    }
}

__global__ __launch_bounds__(512, 2) void ntm_memory_kernel(
    const float* __restrict__ memory, const float* __restrict__ key,
    const float* __restrict__ beta, const float* __restrict__ g,
    const float* __restrict__ s, const float* __restrict__ gamma,
    const float* __restrict__ w_prev, const float* __restrict__ e,
    const float* __restrict__ a, float* __restrict__ out) {
    const int b    = blockIdx.x;
    const int t    = threadIdx.x;
    const int lane = t & 63;
    const int wave = t >> 6;          // 0..7
    const int sub  = lane >> 4;       // 0..3  row within group
    const int sl   = lane & 15;       // 0..15 lanes per row

    __shared__ float key_lds[MM];
    __shared__ float sc[NN];
    __shared__ float wg[NN];
    __shared__ float wf[NN];
    __shared__ float ea_lds[2 * MM];
    __shared__ float red[8];
    __shared__ float rpart[8][MM];

    const float* __restrict__ memb = memory + (size_t)b * NN * MM;
    float* __restrict__ outb       = out + (size_t)b * OUTROW;

    // ---- stage key (+eps), e, a ----
    if (t < MM) {
        key_lds[t]      = key[b * MM + t] + EPS_ADD;
        ea_lds[MM + t]  = a[b * MM + t];
    } else {
        const int i = t - MM;
        ea_lds[i] = e[b * MM + i];
    }
    __syncthreads();

    // ---- key norm ----
    if (t < MM) {
        float kv = key_lds[t];
        float ss = waveReduceSum(kv * kv);
        if (lane == 0) red[wave] = ss;
    }
    __syncthreads();
    const float kn  = fmaxf(sqrtf(red[0] + red[1] + red[2] + red[3]), EPS_COS);
    const float bet = beta[b];
    const float gv  = g[b];
    const float gam = gamma[b];
    const float s0  = s[b * 3 + 0];
    const float s1  = s[b * 3 + 1];
    const float s2  = s[b * 3 + 2];
    __syncthreads();   // red about to be reused

    const int rowbase = wave * 64 + sub;          // row of group gp = rowbase + 4*gp
    const float* __restrict__ rp0 = memb + (size_t)rowbase * MM + sl * 4;

    f4v kf[4];
#pragma unroll
    for (int mc = 0; mc < 4; ++mc)
        kf[mc] = *reinterpret_cast<const f4v*>(&key_lds[mc * 64 + sl * 4]);

    // ---- phase 1a: register tile (44 live-out NT loads => deep MLP) ----
    f4v tile[G_REG][4];
#pragma unroll
    for (int gp = 0; gp < G_REG; ++gp)
        ldgrp_nt(tile[gp], rp0 + (size_t)(4 * gp) * MM);

    // reduce register groups (vmcnt staggers through the burst)
#pragma unroll
    for (int gp = 0; gp < G_REG; ++gp)
        redgrp(tile[gp], kf, bet, kn, sc, rowbase + 4 * gp, sl);

    // ---- phase 1b: 5 streaming groups, 2-deep pipelined, cacheable ----
    {
        f4v sA[4], sB[4];
        ldgrp(sA, rp0 + (size_t)(4 * (G_REG + 0)) * MM);
        ldgrp(sB, rp0 + (size_t)(4 * (G_REG + 1)) * MM);
        redgrp(sA, kf, bet, kn, sc, rowbase + 4 * (G_REG + 0), sl);
        ldgrp(sA, rp0 + (size_t)(4 * (G_REG + 2)) * MM);
        redgrp(sB, kf, bet, kn, sc, rowbase + 4 * (G_REG + 1), sl);
        ldgrp(sB, rp0 + (size_t)(4 * (G_REG + 3)) * MM);
        redgrp(sA, kf, bet, kn, sc, rowbase + 4 * (G_REG + 2), sl);
        ldgrp(sA, rp0 + (size_t)(4 * (G_REG + 4)) * MM);
        redgrp(sB, kf, bet, kn, sc, rowbase + 4 * (G_REG + 3), sl);
        redgrp(sA, kf, bet, kn, sc, rowbase + 4 * (G_REG + 4), sl);
    }
    __syncthreads();

    // ---- softmax over N=512, NO max pass (scores = beta*cos in [-1,1]) ----
    const float v  = sc[t];
    const float ex = __expf(v);
    {
        const float s1w = waveReduceSum(ex);
        if (lane == 0) red[wave] = s1w;
    }
    __syncthreads();
    float esum = 0.f;
#pragma unroll
    for (int k = 0; k < 8; k++) esum += red[k];
    const float w_c = ex / esum;

    // ---- gate + circular conv + sharpen ----
    wg[t] = gv * w_c + (1.f - gv) * w_prev[b * NN + t];
    __syncthreads();
    const float wt = wg[(t + NN - 1) & (NN - 1)] * s0 + wg[t] * s1 +
                     wg[(t + 1) & (NN - 1)] * s2;
    const float wp = __powf(wt, gam);
    {
        const float sw = waveReduceSum(wp);
        if (lane == 0) red[wave] = sw;
    }
    __syncthreads();
    float wsum = 0.f;
#pragma unroll
    for (int k = 0; k < 8; k++) wsum += red[k];
    const float wv = wp / (wsum + EPS_ADD);
    wf[t]   = wv;
    outb[t] = wv;      // output w
    // NO barrier: phase 2 reads wf only within this wave's own 64-row slab,
    // written by lanes of the same wave (intra-wave LDS ordering suffices).

    // ---- phase 2: new_mem + r ----
    f4v ev[4], av[4], acc[4];
#pragma unroll
    for (int mc = 0; mc < 4; ++mc) {
        ev[mc]  = *reinterpret_cast<const f4v*>(&ea_lds[mc * 64 + sl * 4]);
        av[mc]  = *reinterpret_cast<const f4v*>(&ea_lds[MM + mc * 64 + sl * 4]);
        acc[mc] = (f4v)0.f;
    }
    float* __restrict__ ob0 = outb + (NN + MM) + (size_t)rowbase * MM + sl * 4;

    // register-resident groups: pure compute + NT store
#pragma unroll
    for (int gp = 0; gp < G_REG; ++gp)
        procgrp(tile[gp], wf[rowbase + 4 * gp], ev, av, acc,
                ob0 + (size_t)(4 * gp) * MM);

    // streaming groups: re-read (L2/L3-resident), 2-deep
    {
        f4v sA[4], sB[4];
        ldgrp(sA, rp0 + (size_t)(4 * (G_REG + 0)) * MM);
        ldgrp(sB, rp0 + (size_t)(4 * (G_REG + 1)) * MM);
        procgrp(sA, wf[rowbase + 4 * (G_REG + 0)], ev, av, acc,
                ob0 + (size_t)(4 * (G_REG + 0)) * MM);
        ldgrp(sA, rp0 + (size_t)(4 * (G_REG + 2)) * MM);
        procgrp(sB, wf[rowbase + 4 * (G_REG + 1)], ev, av, acc,
                ob0 + (size_t)(4 * (G_REG + 1)) * MM);
        ldgrp(sB, rp0 + (size_t)(4 * (G_REG + 3)) * MM);
        procgrp(sA, wf[rowbase + 4 * (G_REG + 2)], ev, av, acc,
                ob0 + (size_t)(4 * (G_REG + 2)) * MM);
        ldgrp(sA, rp0 + (size_t)(4 * (G_REG + 4)) * MM);
        procgrp(sB, wf[rowbase + 4 * (G_REG + 3)], ev, av, acc,
                ob0 + (size_t)(4 * (G_REG + 3)) * MM);
        procgrp(sA, wf[rowbase + 4 * (G_REG + 4)], ev, av, acc,
                ob0 + (size_t)(4 * (G_REG + 4)) * MM);
    }

    // reduce r partials across the 4 sub-rows of the wave
#pragma unroll
    for (int mc = 0; mc < 4; ++mc) {
        acc[mc].x += __shfl_xor(acc[mc].x, 16); acc[mc].y += __shfl_xor(acc[mc].y, 16);
        acc[mc].z += __shfl_xor(acc[mc].z, 16); acc[mc].w += __shfl_xor(acc[mc].w, 16);
        acc[mc].x += __shfl_xor(acc[mc].x, 32); acc[mc].y += __shfl_xor(acc[mc].y, 32);
        acc[mc].z += __shfl_xor(acc[mc].z, 32); acc[mc].w += __shfl_xor(acc[mc].w, 32);
    }
    if (sub == 0) {
#pragma unroll
        for (int mc = 0; mc < 4; ++mc)
            *reinterpret_cast<f4v*>(&rpart[wave][mc * 64 + sl * 4]) = acc[mc];
    }
    __syncthreads();
    if (t < MM) {
        float rsum = 0.f;
#pragma unroll
        for (int k = 0; k < 8; k++) rsum += rpart[k][t];
        outb[NN + t] = rsum;   // output r
    }
}

extern "C" void kernel_launch(void* const* d_in, const int* in_sizes, int n_in,
                              void* d_out, int out_size, void* d_ws, size_t ws_size,
                              hipStream_t stream) {
    const float* memory = (const float*)d_in[0];
    const float* key    = (const float*)d_in[1];
    const float* beta   = (const float*)d_in[2];
    const float* g      = (const float*)d_in[3];
    const float* s      = (const float*)d_in[4];
    const float* gamma  = (const float*)d_in[5];
    const float* w_prev = (const float*)d_in[6];
    const float* e      = (const float*)d_in[7];
    const float* a      = (const float*)d_in[8];
    float* out = (float*)d_out;

    ntm_memory_kernel<<<BB, 512, 0, stream>>>(memory, key, beta, g, s, gamma,
                                              w_prev, e, a, out);
}